// Round 3
// baseline (983.196 us; speedup 1.0000x reference)
//
#include <hip/hip_runtime.h>

// ---------- types ----------
typedef __attribute__((ext_vector_type(8))) short bf16x8;
typedef __attribute__((ext_vector_type(4))) float f32x4;

static __device__ __forceinline__ unsigned short f2bf(float x) {
    unsigned int u = __float_as_uint(x);
    u += 0x7fffu + ((u >> 16) & 1u);   // RTNE, finite inputs
    return (unsigned short)(u >> 16);
}

// Workgroup barrier WITHOUT vmcnt drain: LDS ordering only.
// Safe when no global-memory producer/consumer relationship crosses the barrier.
static __device__ __forceinline__ void barrier_lds_only() {
    __asm__ volatile("s_waitcnt lgkmcnt(0)\n\ts_barrier" ::: "memory");
}

// ---------- K0: four fp32->bf16 transposes in one launch ----------
__global__ void transpose4(const float* __restrict__ s0, const float* __restrict__ s1,
                           const float* __restrict__ s2, const float* __restrict__ s3,
                           unsigned short* __restrict__ d0, unsigned short* __restrict__ d1,
                           unsigned short* __restrict__ d2, unsigned short* __restrict__ d3) {
    int which = blockIdx.y;
    const float* src = which == 0 ? s0 : which == 1 ? s1 : which == 2 ? s2 : s3;
    unsigned short* dst = which == 0 ? d0 : which == 1 ? d1 : which == 2 ? d2 : d3;
    int K = (which == 0) ? 512 : 256;
    int idx = blockIdx.x * 256 + threadIdx.x;
    if (idx >= K * 256) return;
    int k = idx >> 8;          // N = 256
    int n = idx & 255;
    dst[n * K + k] = f2bf(src[idx]);
}

// ---------- GEMM: C[M,N] = A[M,K] @ Bt[N,K]^T + bias, bf16 MFMA ----------
template<bool GATHER>
__global__ __launch_bounds__(256, 4) void gemm_mfma(
    const void* __restrict__ Aptr, const int* __restrict__ tokens,
    const unsigned short* __restrict__ Bt, const float* __restrict__ bias,
    float* __restrict__ C, int M, int N, int K)
{
    const int bn0 = blockIdx.x * 64;
    const int m0  = blockIdx.y * 64;
    const int tid = threadIdx.x;

    __shared__ unsigned short As[64 * 40];
    __shared__ unsigned short Bs[64 * 40];
    __shared__ int tok[64];

    if (GATHER) {
        if (tid < 64) tok[tid] = tokens[m0 + tid];
        __syncthreads();
    }

    const int r  = tid >> 2;
    const int c0 = (tid & 3) * 8;
    const int w  = tid >> 6;
    const int L  = tid & 63;
    const int ml = L & 15;
    const int q  = L >> 4;
    const int kq = q * 8;

    f32x4 acc[4] = {};

    for (int k0 = 0; k0 < K; k0 += 32) {
        unsigned short tmp[8];
        if (GATHER) {
            const float* src = (const float*)Aptr + (size_t)tok[r] * K + k0 + c0;
            float4 f0 = *(const float4*)(src);
            float4 f1 = *(const float4*)(src + 4);
            tmp[0]=f2bf(f0.x); tmp[1]=f2bf(f0.y); tmp[2]=f2bf(f0.z); tmp[3]=f2bf(f0.w);
            tmp[4]=f2bf(f1.x); tmp[5]=f2bf(f1.y); tmp[6]=f2bf(f1.z); tmp[7]=f2bf(f1.w);
        } else {
            const unsigned short* src = (const unsigned short*)Aptr + (size_t)(m0 + r) * K + k0 + c0;
            *(uint4*)tmp = *(const uint4*)src;
        }
        *(uint4*)&As[r * 40 + c0] = *(const uint4*)tmp;
        *(uint4*)&Bs[r * 40 + c0] = *(const uint4*)(Bt + (size_t)(bn0 + r) * K + k0 + c0);
        __syncthreads();

        bf16x8 av = *(const bf16x8*)&As[(16 * w + ml) * 40 + kq];
#pragma unroll
        for (int ns = 0; ns < 4; ++ns) {
            bf16x8 bv = *(const bf16x8*)&Bs[(ns * 16 + ml) * 40 + kq];
            acc[ns] = __builtin_amdgcn_mfma_f32_16x16x32_bf16(av, bv, acc[ns], 0, 0, 0);
        }
        __syncthreads();
    }

#pragma unroll
    for (int ns = 0; ns < 4; ++ns) {
        int gn = bn0 + ns * 16 + ml;
        float bv = bias[gn];
#pragma unroll
        for (int rr = 0; rr < 4; ++rr) {
            int gm = m0 + 16 * w + q * 4 + rr;
            C[(size_t)gm * N + gn] = acc[ns][rr] + bv;
        }
    }
}

// ---------- K2: fused layer-1 scan + W2-GEMV ----------
// h1[t] = tanh(xw1[t] + h1[t-1]@U1);  p[t-1] = h1[t-1]@W2 + b2, stored IN PLACE
// into xw slot t-1 (that slot was prefetched 5 ticks earlier, same thread column
// -> no hazard). Eliminates the separate xw2 GEMM and all h1 global traffic.
// The W2 MFMAs reuse the same af fragments and fill the U1 chain's stall slots.
// U1 ladder: 4 accs/tile (dep chain 2); W2 ladder: 2 accs/tile (dep chain 4).
__global__ __launch_bounds__(256, 1) void rnn_scan_fused(
    float* __restrict__ xw,                 // [64][512][256] f32; in: xw1, out: p(+b2)
    const unsigned short* __restrict__ U1t, // [256][256] bf16 [n][k]
    const unsigned short* __restrict__ W2t, // [256][256] bf16 [n][k]
    const float* __restrict__ b2)           // [256]
{
    const int b   = blockIdx.x;
    const int tid = threadIdx.x;
    const int w   = tid >> 6;
    const int L   = tid & 63;
    const int col = tid;
    const int q   = L >> 4;
    const int ml  = L & 15;

    __shared__ unsigned short hsh[2][256];

    bf16x8 U1f[4][8], W2f[4][8];
#pragma unroll
    for (int i = 0; i < 4; ++i) {
        const unsigned short* u1 = U1t + (size_t)((w * 4 + i) * 16 + ml) * 256 + q * 8;
        const unsigned short* w2 = W2t + (size_t)((w * 4 + i) * 16 + ml) * 256 + q * 8;
#pragma unroll
        for (int kt = 0; kt < 8; ++kt) {
            U1f[i][kt] = *(const bf16x8*)(u1 + kt * 32);
            W2f[i][kt] = *(const bf16x8*)(w2 + kt * 32);
        }
    }

    hsh[0][tid] = 0;
    const float b2c = b2[col];
    float* xb        = xw + (size_t)b * 512 * 256 + col;
    const float* xpf = xb + 4 * 256;
    float* pst       = xb - 256;          // store target for p[t-1]; bumped every tick
    float xq0 = xb[0 * 256], xq1 = xb[1 * 256], xq2 = xb[2 * 256], xq3 = xb[3 * 256];
    const f32x4 z4 = {0.f, 0.f, 0.f, 0.f};
    __syncthreads();

#define FTICK(RP, XQ, PF, ST)                                                        \
    {                                                                                \
        bf16x8 af[8];                                                                \
        _Pragma("unroll")                                                            \
        for (int kt = 0; kt < 8; ++kt)                                               \
            af[kt] = *(const bf16x8*)&hsh[RP][kt * 32 + q * 8];                      \
        float xnew = 0.f;                                                            \
        if (PF) { xnew = *xpf; xpf += 256; }                                         \
        f32x4 aU[4][4];                                                              \
        f32x4 aW[4][2];                                                              \
        _Pragma("unroll")                                                            \
        for (int kt = 0; kt < 8; ++kt) {                                             \
            _Pragma("unroll")                                                        \
            for (int i = 0; i < 4; ++i)                                              \
                aU[i][kt & 3] = __builtin_amdgcn_mfma_f32_16x16x32_bf16(             \
                    af[kt], U1f[i][kt], (kt < 4) ? z4 : aU[i][kt & 3], 0, 0, 0);     \
            _Pragma("unroll")                                                        \
            for (int i = 0; i < 4; ++i)                                              \
                aW[i][kt & 1] = __builtin_amdgcn_mfma_f32_16x16x32_bf16(             \
                    af[kt], W2f[i][kt], (kt < 2) ? z4 : aW[i][kt & 1], 0, 0, 0);     \
        }                                                                            \
        float sU0 = aU[0][0][0] + aU[0][1][0] + aU[0][2][0] + aU[0][3][0];           \
        float sU1 = aU[1][0][0] + aU[1][1][0] + aU[1][2][0] + aU[1][3][0];           \
        float sU2 = aU[2][0][0] + aU[2][1][0] + aU[2][2][0] + aU[2][3][0];           \
        float sU3 = aU[3][0][0] + aU[3][1][0] + aU[3][2][0] + aU[3][3][0];           \
        float z = ((q == 0) ? sU0 : (q == 1) ? sU1 : (q == 2) ? sU2 : sU3) + XQ;     \
        float e  = __expf(2.f * z);               /* tanh(z) = 1 - 2/(e^{2z}+1) */   \
        float hn = 1.f - 2.f * __builtin_amdgcn_rcpf(e + 1.f);                       \
        hsh[(RP) ^ 1][col] = f2bf(hn);                                               \
        if (ST) {                                                                    \
            float sW0 = aW[0][0][0] + aW[0][1][0];                                   \
            float sW1 = aW[1][0][0] + aW[1][1][0];                                   \
            float sW2 = aW[2][0][0] + aW[2][1][0];                                   \
            float sW3 = aW[3][0][0] + aW[3][1][0];                                   \
            *pst = ((q == 0) ? sW0 : (q == 1) ? sW1 : (q == 2) ? sW2 : sW3) + b2c;   \
        }                                                                            \
        pst += 256;                                                                  \
        XQ = xnew;                                                                   \
        barrier_lds_only();                                                          \
    }

    // peel ticks 0..3 (t=0 has no p[-1] store)
    FTICK(0, xq0, 1, 0)
    FTICK(1, xq1, 1, 1)
    FTICK(0, xq2, 1, 1)
    FTICK(1, xq3, 1, 1)
    // ticks 4..507
    for (int tt = 4; tt < 508; tt += 4) {
        FTICK(0, xq0, 1, 1)
        FTICK(1, xq1, 1, 1)
        FTICK(0, xq2, 1, 1)
        FTICK(1, xq3, 1, 1)
    }
    // ticks 508..511: no prefetch
    FTICK(0, xq0, 0, 1)
    FTICK(1, xq1, 0, 1)
    FTICK(0, xq2, 0, 1)
    FTICK(1, xq3, 0, 1)
#undef FTICK

    // extra W2-only tick: p[511] from h1[511] (in hsh[0]); pst now = xb + 511*256
    {
        bf16x8 af[8];
#pragma unroll
        for (int kt = 0; kt < 8; ++kt)
            af[kt] = *(const bf16x8*)&hsh[0][kt * 32 + q * 8];
        f32x4 aW[4][2];
#pragma unroll
        for (int kt = 0; kt < 8; ++kt)
#pragma unroll
            for (int i = 0; i < 4; ++i)
                aW[i][kt & 1] = __builtin_amdgcn_mfma_f32_16x16x32_bf16(
                    af[kt], W2f[i][kt], (kt < 2) ? z4 : aW[i][kt & 1], 0, 0, 0);
        float sW0 = aW[0][0][0] + aW[0][1][0];
        float sW1 = aW[1][0][0] + aW[1][1][0];
        float sW2 = aW[2][0][0] + aW[2][1][0];
        float sW3 = aW[3][0][0] + aW[3][1][0];
        *pst = ((q == 0) ? sW0 : (q == 1) ? sW1 : (q == 2) ? sW2 : sW3) + b2c;
    }
}

// ---------- K3: layer-2 scan (reads p+b2 from xw), depth-2 MFMA chain ----------
__global__ __launch_bounds__(256, 1) void rnn_scan2(
    const float* __restrict__ xw,           // [64][512][256] f32 = p + b2
    const unsigned short* __restrict__ Ut,  // U2t [256][256] bf16 [n][k]
    float* __restrict__ out_last)           // [64][256] f32
{
    const int b   = blockIdx.x;
    const int tid = threadIdx.x;
    const int w   = tid >> 6;
    const int L   = tid & 63;
    const int col = tid;
    const int q   = L >> 4;
    const int ml  = L & 15;

    __shared__ unsigned short hsh[2][256];

    bf16x8 uf[4][8];
#pragma unroll
    for (int i = 0; i < 4; ++i) {
        const unsigned short* up = Ut + (size_t)((w * 4 + i) * 16 + ml) * 256 + q * 8;
#pragma unroll
        for (int kt = 0; kt < 8; ++kt)
            uf[kt == 0 ? i : i][kt] = *(const bf16x8*)(up + kt * 32);
    }

    hsh[0][tid] = 0;
    const float* xb  = xw + (size_t)b * 512 * 256 + col;
    const float* xpf = xb + 4 * 256;
    float xq0 = xb[0 * 256], xq1 = xb[1 * 256], xq2 = xb[2 * 256], xq3 = xb[3 * 256];
    const f32x4 z4 = {0.f, 0.f, 0.f, 0.f};
    float lastv = 0.f;
    __syncthreads();

#define STICK(RP, XQ, PF)                                                            \
    {                                                                                \
        bf16x8 af[8];                                                                \
        _Pragma("unroll")                                                            \
        for (int kt = 0; kt < 8; ++kt)                                               \
            af[kt] = *(const bf16x8*)&hsh[RP][kt * 32 + q * 8];                      \
        float xnew = 0.f;                                                            \
        if (PF) { xnew = *xpf; xpf += 256; }                                         \
        f32x4 aU[4][4];                                                              \
        _Pragma("unroll")                                                            \
        for (int kt = 0; kt < 8; ++kt) {                                             \
            _Pragma("unroll")                                                        \
            for (int i = 0; i < 4; ++i)                                              \
                aU[i][kt & 3] = __builtin_amdgcn_mfma_f32_16x16x32_bf16(             \
                    af[kt], uf[i][kt], (kt < 4) ? z4 : aU[i][kt & 3], 0, 0, 0);      \
        }                                                                            \
        float s0 = aU[0][0][0] + aU[0][1][0] + aU[0][2][0] + aU[0][3][0];            \
        float s1 = aU[1][0][0] + aU[1][1][0] + aU[1][2][0] + aU[1][3][0];            \
        float s2 = aU[2][0][0] + aU[2][1][0] + aU[2][2][0] + aU[2][3][0];            \
        float s3 = aU[3][0][0] + aU[3][1][0] + aU[3][2][0] + aU[3][3][0];            \
        float z = ((q == 0) ? s0 : (q == 1) ? s1 : (q == 2) ? s2 : s3) + XQ;         \
        float e  = __expf(2.f * z);                                                  \
        float hn = 1.f - 2.f * __builtin_amdgcn_rcpf(e + 1.f);                       \
        lastv = hn;                                                                  \
        hsh[(RP) ^ 1][col] = f2bf(hn);                                               \
        XQ = xnew;                                                                   \
        barrier_lds_only();                                                          \
    }

    for (int tt = 0; tt < 508; tt += 4) {
        STICK(0, xq0, 1)
        STICK(1, xq1, 1)
        STICK(0, xq2, 1)
        STICK(1, xq3, 1)
    }
    STICK(0, xq0, 0)
    STICK(1, xq1, 0)
    STICK(0, xq2, 0)
    STICK(1, xq3, 0)
#undef STICK

    out_last[b * 256 + col] = lastv;
}

// ---------- head: softmax(h2 @ Wd + bd) ----------
__global__ void head_kernel(const float* __restrict__ h2, const float* __restrict__ Wd,
                            const float* __restrict__ bd, float* __restrict__ out)
{
    int tid = threadIdx.x;         // 128 threads: b = tid>>1, c = tid&1
    int b = tid >> 1, c = tid & 1;
    float s = bd[c];
    for (int jj = 0; jj < 256; ++jj) s = fmaf(h2[b * 256 + jj], Wd[jj * 2 + c], s);
    __shared__ float lg[128];
    lg[tid] = s;
    __syncthreads();
    float o0 = lg[b * 2 + 0], o1 = lg[b * 2 + 1];
    float m = fmaxf(o0, o1);
    float z = __expf(o0 - m) + __expf(o1 - m);
    out[tid] = __expf(s - m) * __builtin_amdgcn_rcpf(z);
}

// ---------- launch ----------
extern "C" void kernel_launch(void* const* d_in, const int* in_sizes, int n_in,
                              void* d_out, int out_size, void* d_ws, size_t ws_size,
                              hipStream_t stream) {
    const int*   tokens = (const int*)d_in[0];
    const float* emb    = (const float*)d_in[1];
    const float* W1     = (const float*)d_in[2];
    const float* U1     = (const float*)d_in[3];
    const float* b1     = (const float*)d_in[4];
    const float* W2     = (const float*)d_in[5];
    const float* U2     = (const float*)d_in[6];
    const float* b2     = (const float*)d_in[7];
    const float* Wd     = (const float*)d_in[8];
    const float* bd     = (const float*)d_in[9];
    float* out = (float*)d_out;

    char* ws = (char*)d_ws;
    float*          xw  = (float*)ws;                                  // 32 MB (xw1, overwritten by p)
    char*           p   = ws + 33554432 + 16777216;                    // weights (unchanged offsets)
    unsigned short* W1t = (unsigned short*)p;            p += 512 * 256 * 2;
    unsigned short* W2t = (unsigned short*)p;            p += 256 * 256 * 2;
    unsigned short* U1t = (unsigned short*)p;            p += 256 * 256 * 2;
    unsigned short* U2t = (unsigned short*)p;            p += 256 * 256 * 2;
    float*          h2  = (float*)p;

    const int M = 64 * 512;   // 32768

    // K0: weight/recurrence transposes to bf16 [N][K]
    transpose4<<<dim3(512, 4), 256, 0, stream>>>(W1, W2, U1, U2, W1t, W2t, U1t, U2t);

    // K1: xw1 = emb[tokens] @ W1 + b1   (gather fused)
    gemm_mfma<true><<<dim3(256 / 64, M / 64), 256, 0, stream>>>(
        emb, tokens, W1t, b1, xw, M, 256, 512);

    // K2: fused layer-1 scan + W2-GEMV; xw becomes p = h1@W2 + b2
    rnn_scan_fused<<<64, 256, 0, stream>>>(xw, U1t, W2t, b2);

    // K3: layer-2 scan -> h2 (last state, f32)
    rnn_scan2<<<64, 256, 0, stream>>>(xw, U2t, h2);

    // K4: softmax(h2 @ Wd + bd)
    head_kernel<<<1, 128, 0, stream>>>(h2, Wd, bd, out);
}

// Round 4
// 878.319 us; speedup vs baseline: 1.1194x; 1.1194x over previous
//
#include <hip/hip_runtime.h>

// ---------- types ----------
typedef __attribute__((ext_vector_type(8))) short bf16x8;
typedef __attribute__((ext_vector_type(4))) float f32x4;

static __device__ __forceinline__ unsigned short f2bf(float x) {
    unsigned int u = __float_as_uint(x);
    u += 0x7fffu + ((u >> 16) & 1u);   // RTNE, finite inputs
    return (unsigned short)(u >> 16);
}

static __device__ __forceinline__ float selq(const f32x4* a, int q) {
    return (q == 0) ? a[0][0] : (q == 1) ? a[1][0] : (q == 2) ? a[2][0] : a[3][0];
}

// Workgroup barrier WITHOUT vmcnt drain: LDS ordering only.
static __device__ __forceinline__ void barrier_lds_only() {
    __asm__ volatile("s_waitcnt lgkmcnt(0)\n\ts_barrier" ::: "memory");
}

// ---------- K0: four fp32->bf16 transposes in one launch ----------
__global__ void transpose4(const float* __restrict__ s0, const float* __restrict__ s1,
                           const float* __restrict__ s2, const float* __restrict__ s3,
                           unsigned short* __restrict__ d0, unsigned short* __restrict__ d1,
                           unsigned short* __restrict__ d2, unsigned short* __restrict__ d3) {
    int which = blockIdx.y;
    const float* src = which == 0 ? s0 : which == 1 ? s1 : which == 2 ? s2 : s3;
    unsigned short* dst = which == 0 ? d0 : which == 1 ? d1 : which == 2 ? d2 : d3;
    int K = (which == 0) ? 512 : 256;
    int idx = blockIdx.x * 256 + threadIdx.x;
    if (idx >= K * 256) return;
    int k = idx >> 8;          // N = 256
    int n = idx & 255;
    dst[n * K + k] = f2bf(src[idx]);
}

// ---------- K1 GEMM: C[M,N] = A[M,K] @ Bt[N,K]^T + bias, bf16 MFMA ----------
template<bool GATHER>
__global__ __launch_bounds__(256, 4) void gemm_mfma(
    const void* __restrict__ Aptr, const int* __restrict__ tokens,
    const unsigned short* __restrict__ Bt, const float* __restrict__ bias,
    float* __restrict__ C, int M, int N, int K)
{
    const int bn0 = blockIdx.x * 64;
    const int m0  = blockIdx.y * 64;
    const int tid = threadIdx.x;

    __shared__ unsigned short As[64 * 40];
    __shared__ unsigned short Bs[64 * 40];
    __shared__ int tok[64];

    if (GATHER) {
        if (tid < 64) tok[tid] = tokens[m0 + tid];
        __syncthreads();
    }

    const int r  = tid >> 2;
    const int c0 = (tid & 3) * 8;
    const int w  = tid >> 6;
    const int L  = tid & 63;
    const int ml = L & 15;
    const int q  = L >> 4;
    const int kq = q * 8;

    f32x4 acc[4] = {};

    for (int k0 = 0; k0 < K; k0 += 32) {
        unsigned short tmp[8];
        if (GATHER) {
            const float* src = (const float*)Aptr + (size_t)tok[r] * K + k0 + c0;
            float4 f0 = *(const float4*)(src);
            float4 f1 = *(const float4*)(src + 4);
            tmp[0]=f2bf(f0.x); tmp[1]=f2bf(f0.y); tmp[2]=f2bf(f0.z); tmp[3]=f2bf(f0.w);
            tmp[4]=f2bf(f1.x); tmp[5]=f2bf(f1.y); tmp[6]=f2bf(f1.z); tmp[7]=f2bf(f1.w);
        } else {
            const unsigned short* src = (const unsigned short*)Aptr + (size_t)(m0 + r) * K + k0 + c0;
            *(uint4*)tmp = *(const uint4*)src;
        }
        *(uint4*)&As[r * 40 + c0] = *(const uint4*)tmp;
        *(uint4*)&Bs[r * 40 + c0] = *(const uint4*)(Bt + (size_t)(bn0 + r) * K + k0 + c0);
        __syncthreads();

        bf16x8 av = *(const bf16x8*)&As[(16 * w + ml) * 40 + kq];
#pragma unroll
        for (int ns = 0; ns < 4; ++ns) {
            bf16x8 bv = *(const bf16x8*)&Bs[(ns * 16 + ml) * 40 + kq];
            acc[ns] = __builtin_amdgcn_mfma_f32_16x16x32_bf16(av, bv, acc[ns], 0, 0, 0);
        }
        __syncthreads();
    }

#pragma unroll
    for (int ns = 0; ns < 4; ++ns) {
        int gn = bn0 + ns * 16 + ml;
        float bv = bias[gn];
#pragma unroll
        for (int rr = 0; rr < 4; ++rr) {
            int gm = m0 + 16 * w + q * 4 + rr;
            C[(size_t)gm * N + gn] = acc[ns][rr] + bv;
        }
    }
}

// ---------- K2: cross-CU pipelined scans ----------
// 128 blocks x 256 threads (all co-resident: 128 <= 256 CUs).
//  blocks 0..63  (producer, batch b): EXACT baseline layer-1 scan (439ns/tick),
//      storing h1[t] bf16 to global; every 8 ticks: vmcnt(0)-drain barrier, then
//      tid0 publishes flag=t+1 with RELEASE/AGENT (orders all waves' h1 stores).
//  blocks 64..127 (consumer, batch b-64): layer-2 scan with the W2-GEMV fused:
//      h2[t] = tanh(h1[t]@W2 + b2 + h2[t-1]@U2). h1[t] fragments come from
//      global (plain loads, 2-tick register prefetch), gated per-8-tick group by
//      the flag (ACQUIRE/AGENT, bounded spin -> no-hang guarantee). Block b and
//      64+b land on the same XCD under %8 round-robin, so the handoff is L2-local.
// Producer never waits on consumer => no deadlock cycle.
__global__ __launch_bounds__(256, 1) void rnn_pipe(
    const float* __restrict__ xw,             // [64][512][256] f32 (= emb@W1+b1)
    const unsigned short* __restrict__ U1t,   // [256][256] bf16 [n][k]
    const unsigned short* __restrict__ W2t,   // [256][256] bf16 [n][k]
    const unsigned short* __restrict__ U2t,   // [256][256] bf16 [n][k]
    const float* __restrict__ b2,             // [256]
    unsigned short* h1g,                      // [64][512][256] bf16 handoff
    int* flags,                               // [64], zeroed before launch
    float* __restrict__ out_last)             // [64][256] f32
{
    const int bid = blockIdx.x;
    const int tid = threadIdx.x;
    const int w   = tid >> 6;
    const int L   = tid & 63;
    const int col = tid;            // w*64 + L
    const int q   = L >> 4;
    const int ml  = L & 15;

    __shared__ unsigned short hsh[2][256];

    if (bid < 64) {
        // ================= producer: baseline scan1 + h1 publish =================
        const int b = bid;
        int* flagp = flags + b;

        bf16x8 U1f[4][8];
#pragma unroll
        for (int i = 0; i < 4; ++i) {
            const unsigned short* up = U1t + (size_t)((w * 4 + i) * 16 + ml) * 256 + q * 8;
#pragma unroll
            for (int kt = 0; kt < 8; ++kt)
                U1f[i][kt] = *(const bf16x8*)(up + kt * 32);
        }
        hsh[0][tid] = 0;

        const float* xb  = xw + (size_t)b * 512 * 256 + col;
        const float* xpf = xb + 4 * 256;
        unsigned short* op = h1g + (((size_t)b * 512) << 8) + col;
        float xq0 = xb[0 * 256], xq1 = xb[1 * 256], xq2 = xb[2 * 256], xq3 = xb[3 * 256];
        __syncthreads();

#define PSTEP(CUR, XQ, PF)                                                           \
    {                                                                                \
        bf16x8 af[8];                                                                \
        _Pragma("unroll")                                                            \
        for (int kt = 0; kt < 8; ++kt)                                               \
            af[kt] = *(const bf16x8*)&hsh[CUR][kt * 32 + q * 8];                     \
        float xnew = 0.f;                                                            \
        if (PF) { xnew = *xpf; xpf += 256; }                                         \
        f32x4 accA[4] = {}, accB[4] = {};                                            \
        _Pragma("unroll")                                                            \
        for (int kt = 0; kt < 8; kt += 2) {                                          \
            _Pragma("unroll")                                                        \
            for (int i = 0; i < 4; ++i)                                              \
                accA[i] = __builtin_amdgcn_mfma_f32_16x16x32_bf16(af[kt], U1f[i][kt], accA[i], 0, 0, 0);       \
            _Pragma("unroll")                                                        \
            for (int i = 0; i < 4; ++i)                                              \
                accB[i] = __builtin_amdgcn_mfma_f32_16x16x32_bf16(af[kt + 1], U1f[i][kt + 1], accB[i], 0, 0, 0); \
        }                                                                            \
        float z  = selq(accA, q) + selq(accB, q) + XQ;                               \
        float e  = __expf(2.f * z);               /* tanh(z) = 1 - 2/(e^{2z}+1) */   \
        float hn = 1.f - 2.f * __builtin_amdgcn_rcpf(e + 1.f);                       \
        unsigned short hb = f2bf(hn);                                                \
        hsh[(CUR) ^ 1][col] = hb;                                                    \
        *op = hb; op += 256;                                                         \
        XQ = xnew;                                                                   \
        barrier_lds_only();                                                          \
    }

        for (int g = 0; g < 63; ++g) {         // ticks 8g..8g+7, all prefetching
            PSTEP(0, xq0, 1) PSTEP(1, xq1, 1) PSTEP(0, xq2, 1) PSTEP(1, xq3, 1)
            PSTEP(0, xq0, 1) PSTEP(1, xq1, 1) PSTEP(0, xq2, 1) PSTEP(1, xq3, 1)
            // all waves drain their h1 stores, sync, then tid0 releases the flag
            asm volatile("s_waitcnt vmcnt(0)" ::: "memory");
            __builtin_amdgcn_s_barrier();
            if (tid == 0)
                __hip_atomic_store(flagp, 8 * g + 8, __ATOMIC_RELEASE, __HIP_MEMORY_SCOPE_AGENT);
        }
        // last group: ticks 504..507 prefetch rows 508..511; 508..511 no prefetch
        PSTEP(0, xq0, 1) PSTEP(1, xq1, 1) PSTEP(0, xq2, 1) PSTEP(1, xq3, 1)
        PSTEP(0, xq0, 0) PSTEP(1, xq1, 0) PSTEP(0, xq2, 0) PSTEP(1, xq3, 0)
#undef PSTEP
        asm volatile("s_waitcnt vmcnt(0)" ::: "memory");
        __builtin_amdgcn_s_barrier();
        if (tid == 0)
            __hip_atomic_store(flagp, 512, __ATOMIC_RELEASE, __HIP_MEMORY_SCOPE_AGENT);
    } else {
        // ================= consumer: scan2 with fused W2-GEMV =================
        const int b = bid - 64;
        int* flagp = flags + b;

        bf16x8 U2f[4][8], W2f[4][8];
#pragma unroll
        for (int i = 0; i < 4; ++i) {
            const unsigned short* u2 = U2t + (size_t)((w * 4 + i) * 16 + ml) * 256 + q * 8;
            const unsigned short* w2 = W2t + (size_t)((w * 4 + i) * 16 + ml) * 256 + q * 8;
#pragma unroll
            for (int kt = 0; kt < 8; ++kt) {
                U2f[i][kt] = *(const bf16x8*)(u2 + kt * 32);
                W2f[i][kt] = *(const bf16x8*)(w2 + kt * 32);
            }
        }
        const float b2c = b2[col];
        hsh[0][tid] = 0;
        const unsigned short* h1b = h1g + (((size_t)b * 512) << 8) + q * 8;
        float lastv = 0.f;
        bf16x8 hA[8], hB[8];
        __syncthreads();

#define LOADH(BUF, T)                                                                \
    {                                                                                \
        const unsigned short* hr = h1b + (((size_t)(T)) << 8);                       \
        _Pragma("unroll")                                                            \
        for (int kt = 0; kt < 8; ++kt)                                               \
            BUF[kt] = *(const bf16x8*)(hr + kt * 32);                                \
    }

#define CSTEP(RP, BUF, PT)                                                           \
    {                                                                                \
        bf16x8 af[8];                                                                \
        _Pragma("unroll")                                                            \
        for (int kt = 0; kt < 8; ++kt)                                               \
            af[kt] = *(const bf16x8*)&hsh[RP][kt * 32 + q * 8];                     \
        f32x4 aA[4] = {}, aB[4] = {}, wA[4] = {}, wB[4] = {};                        \
        _Pragma("unroll")                                                            \
        for (int kt = 0; kt < 8; kt += 2) {                                          \
            _Pragma("unroll")                                                        \
            for (int i = 0; i < 4; ++i)                                              \
                wA[i] = __builtin_amdgcn_mfma_f32_16x16x32_bf16(BUF[kt], W2f[i][kt], wA[i], 0, 0, 0);          \
            _Pragma("unroll")                                                        \
            for (int i = 0; i < 4; ++i)                                              \
                aA[i] = __builtin_amdgcn_mfma_f32_16x16x32_bf16(af[kt], U2f[i][kt], aA[i], 0, 0, 0);           \
            _Pragma("unroll")                                                        \
            for (int i = 0; i < 4; ++i)                                              \
                wB[i] = __builtin_amdgcn_mfma_f32_16x16x32_bf16(BUF[kt + 1], W2f[i][kt + 1], wB[i], 0, 0, 0);  \
            _Pragma("unroll")                                                        \
            for (int i = 0; i < 4; ++i)                                              \
                aB[i] = __builtin_amdgcn_mfma_f32_16x16x32_bf16(af[kt + 1], U2f[i][kt + 1], aB[i], 0, 0, 0);   \
        }                                                                            \
        float z  = selq(aA, q) + selq(aB, q) + selq(wA, q) + selq(wB, q) + b2c;      \
        float e  = __expf(2.f * z);                                                  \
        float hn = 1.f - 2.f * __builtin_amdgcn_rcpf(e + 1.f);                       \
        lastv = hn;                                                                  \
        hsh[(RP) ^ 1][col] = f2bf(hn);                                               \
        if ((PT) >= 0) LOADH(BUF, PT)                                                \
        barrier_lds_only();                                                          \
    }

        for (int g = 0; g < 64; ++g) {
            const int t0 = 8 * g;
            if (tid == 0) {
                int it = 0;   // bounded spin: on coherence failure -> wrong answer, not a hang
                while (__hip_atomic_load(flagp, __ATOMIC_ACQUIRE, __HIP_MEMORY_SCOPE_AGENT) < t0 + 8) {
                    __builtin_amdgcn_s_sleep(2);
                    if (++it > (1 << 17)) break;
                }
            }
            __syncthreads();
            LOADH(hA, t0 + 0)
            LOADH(hB, t0 + 1)
            CSTEP(0, hA, t0 + 2)
            CSTEP(1, hB, t0 + 3)
            CSTEP(0, hA, t0 + 4)
            CSTEP(1, hB, t0 + 5)
            CSTEP(0, hA, t0 + 6)
            CSTEP(1, hB, t0 + 7)
            CSTEP(0, hA, -1)
            CSTEP(1, hB, -1)
        }
#undef CSTEP
#undef LOADH

        out_last[b * 256 + col] = lastv;
    }
}

// ---------- head: softmax(h2 @ Wd + bd) ----------
__global__ void head_kernel(const float* __restrict__ h2, const float* __restrict__ Wd,
                            const float* __restrict__ bd, float* __restrict__ out)
{
    int tid = threadIdx.x;         // 128 threads: b = tid>>1, c = tid&1
    int b = tid >> 1, c = tid & 1;
    float s = bd[c];
    for (int jj = 0; jj < 256; ++jj) s = fmaf(h2[b * 256 + jj], Wd[jj * 2 + c], s);
    __shared__ float lg[128];
    lg[tid] = s;
    __syncthreads();
    float o0 = lg[b * 2 + 0], o1 = lg[b * 2 + 1];
    float m = fmaxf(o0, o1);
    float z = __expf(o0 - m) + __expf(o1 - m);
    out[tid] = __expf(s - m) * __builtin_amdgcn_rcpf(z);
}

// ---------- launch ----------
extern "C" void kernel_launch(void* const* d_in, const int* in_sizes, int n_in,
                              void* d_out, int out_size, void* d_ws, size_t ws_size,
                              hipStream_t stream) {
    const int*   tokens = (const int*)d_in[0];
    const float* emb    = (const float*)d_in[1];
    const float* W1     = (const float*)d_in[2];
    const float* U1     = (const float*)d_in[3];
    const float* b1     = (const float*)d_in[4];
    const float* W2     = (const float*)d_in[5];
    const float* U2     = (const float*)d_in[6];
    const float* b2     = (const float*)d_in[7];
    const float* Wd     = (const float*)d_in[8];
    const float* bd     = (const float*)d_in[9];
    float* out = (float*)d_out;

    char* ws = (char*)d_ws;
    float*          xw  = (float*)ws;                                  // 32 MB
    unsigned short* h1g = (unsigned short*)(ws + 33554432);            // 16 MB bf16 handoff
    char*           p   = ws + 33554432 + 16777216;                    // weights (same offsets as before)
    unsigned short* W1t = (unsigned short*)p;            p += 512 * 256 * 2;
    unsigned short* W2t = (unsigned short*)p;            p += 256 * 256 * 2;
    unsigned short* U1t = (unsigned short*)p;            p += 256 * 256 * 2;
    unsigned short* U2t = (unsigned short*)p;            p += 256 * 256 * 2;
    float*          h2  = (float*)p;                     p += 64 * 256 * 4;
    int*            flags = (int*)p;

    const int M = 64 * 512;   // 32768

    // flags must be 0 before the pipeline kernel (graph-capture-safe async memset)
    hipMemsetAsync(flags, 0, 64 * sizeof(int), stream);

    // K0: weight/recurrence transposes to bf16 [N][K]
    transpose4<<<dim3(512, 4), 256, 0, stream>>>(W1, W2, U1, U2, W1t, W2t, U1t, U2t);

    // K1: xw1 = emb[tokens] @ W1 + b1   (gather fused)
    gemm_mfma<true><<<dim3(256 / 64, M / 64), 256, 0, stream>>>(
        emb, tokens, W1t, b1, xw, M, 256, 512);

    // K2: cross-CU pipelined scan1 -> h1 handoff -> scan2(+W2 GEMV) -> h2
    rnn_pipe<<<128, 256, 0, stream>>>(xw, U1t, W2t, U2t, b2, h1g, flags, h2);

    // K3: softmax(h2 @ Wd + bd)
    head_kernel<<<1, 128, 0, stream>>>(h2, Wd, bd, out);
}

// Round 6
// 620.756 us; speedup vs baseline: 1.5839x; 1.4149x over previous
//
#include <hip/hip_runtime.h>

// ---------- types ----------
typedef __attribute__((ext_vector_type(8))) short bf16x8;
typedef __attribute__((ext_vector_type(4))) float f32x4;

static __device__ __forceinline__ unsigned short f2bf(float x) {
    unsigned int u = __float_as_uint(x);
    u += 0x7fffu + ((u >> 16) & 1u);   // RTNE, finite inputs
    return (unsigned short)(u >> 16);
}

static __device__ __forceinline__ float selq(const f32x4* a, int q) {
    return (q == 0) ? a[0][0] : (q == 1) ? a[1][0] : (q == 2) ? a[2][0] : a[3][0];
}

// Workgroup barrier WITHOUT vmcnt drain: LDS ordering only.
static __device__ __forceinline__ void barrier_lds_only() {
    __asm__ volatile("s_waitcnt lgkmcnt(0)\n\ts_barrier" ::: "memory");
}

// ---------- K0: four fp32->bf16 transposes in one launch ----------
__global__ void transpose4(const float* __restrict__ s0, const float* __restrict__ s1,
                           const float* __restrict__ s2, const float* __restrict__ s3,
                           unsigned short* __restrict__ d0, unsigned short* __restrict__ d1,
                           unsigned short* __restrict__ d2, unsigned short* __restrict__ d3) {
    int which = blockIdx.y;
    const float* src = which == 0 ? s0 : which == 1 ? s1 : which == 2 ? s2 : s3;
    unsigned short* dst = which == 0 ? d0 : which == 1 ? d1 : which == 2 ? d2 : d3;
    int K = (which == 0) ? 512 : 256;
    int idx = blockIdx.x * 256 + threadIdx.x;
    if (idx >= K * 256) return;
    int k = idx >> 8;          // N = 256
    int n = idx & 255;
    dst[n * K + k] = f2bf(src[idx]);
}

// ---------- K1 GEMM: C[M,N] = A[M,K] @ Bt[N,K]^T + bias, bf16 MFMA ----------
template<bool GATHER>
__global__ __launch_bounds__(256, 4) void gemm_mfma(
    const void* __restrict__ Aptr, const int* __restrict__ tokens,
    const unsigned short* __restrict__ Bt, const float* __restrict__ bias,
    float* __restrict__ C, int M, int N, int K)
{
    const int bn0 = blockIdx.x * 64;
    const int m0  = blockIdx.y * 64;
    const int tid = threadIdx.x;

    __shared__ unsigned short As[64 * 40];
    __shared__ unsigned short Bs[64 * 40];
    __shared__ int tok[64];

    if (GATHER) {
        if (tid < 64) tok[tid] = tokens[m0 + tid];
        __syncthreads();
    }

    const int r  = tid >> 2;
    const int c0 = (tid & 3) * 8;
    const int w  = tid >> 6;
    const int L  = tid & 63;
    const int ml = L & 15;
    const int q  = L >> 4;
    const int kq = q * 8;

    f32x4 acc[4] = {};

    for (int k0 = 0; k0 < K; k0 += 32) {
        unsigned short tmp[8];
        if (GATHER) {
            const float* src = (const float*)Aptr + (size_t)tok[r] * K + k0 + c0;
            float4 f0 = *(const float4*)(src);
            float4 f1 = *(const float4*)(src + 4);
            tmp[0]=f2bf(f0.x); tmp[1]=f2bf(f0.y); tmp[2]=f2bf(f0.z); tmp[3]=f2bf(f0.w);
            tmp[4]=f2bf(f1.x); tmp[5]=f2bf(f1.y); tmp[6]=f2bf(f1.z); tmp[7]=f2bf(f1.w);
        } else {
            const unsigned short* src = (const unsigned short*)Aptr + (size_t)(m0 + r) * K + k0 + c0;
            *(uint4*)tmp = *(const uint4*)src;
        }
        *(uint4*)&As[r * 40 + c0] = *(const uint4*)tmp;
        *(uint4*)&Bs[r * 40 + c0] = *(const uint4*)(Bt + (size_t)(bn0 + r) * K + k0 + c0);
        __syncthreads();

        bf16x8 av = *(const bf16x8*)&As[(16 * w + ml) * 40 + kq];
#pragma unroll
        for (int ns = 0; ns < 4; ++ns) {
            bf16x8 bv = *(const bf16x8*)&Bs[(ns * 16 + ml) * 40 + kq];
            acc[ns] = __builtin_amdgcn_mfma_f32_16x16x32_bf16(av, bv, acc[ns], 0, 0, 0);
        }
        __syncthreads();
    }

#pragma unroll
    for (int ns = 0; ns < 4; ++ns) {
        int gn = bn0 + ns * 16 + ml;
        float bv = bias[gn];
#pragma unroll
        for (int rr = 0; rr < 4; ++rr) {
            int gm = m0 + 16 * w + q * 4 + rr;
            C[(size_t)gm * N + gn] = acc[ns][rr] + bv;
        }
    }
}

// ---------- K2: 2-stage cross-CU pipeline, role-split waves ----------
// 128 blocks x 512 threads (8 waves), all co-resident (128 <= 256 CUs).
// Producer blocks 0..63 (batch b):
//   waves 0-3: baseline layer-1 scan (h1 kept in LDS only, no global h1).
//   waves 4-7: one tick behind, read the SAME LDS h1 buffer and compute
//              p[t-1] = h1[t-1]@W2 + b2 -> f32 store into xw row t-1 (that row's
//              last read was 5 ticks earlier, same block; waves 0-3's code path
//              has NO xw stores so no compiler-alias stalls).
//   Every 8 ticks: vmcnt(0) drain -> s_barrier -> tid0 RELEASE flag = rows done.
// Consumer blocks 64..127 (batch b-64, same XCD as b under %8 dispatch):
//   waves 0-3: baseline layer-2 scan; per 16-tick chunk, bounded-spin ACQUIRE on
//              flag then load pv[16]. waves 4-7: idle, barriers only.
// REGISTER RULE (r3/r4 post-mortem): arch VGPRs cap at 256/wave; each WAVE here
// holds exactly ONE 128-reg fragment set. 2 waves/SIMD x ~230 <= 512 pool.
// All spins bounded -> coherence failure = wrong answer, never a hang.
__global__ __launch_bounds__(512) void rnn_pipe(
    float* xw,                                // [64][512][256] f32: xw1, rows become p
    const unsigned short* __restrict__ U1t,   // [256][256] bf16 [n][k]
    const unsigned short* __restrict__ W2t,   // [256][256] bf16 [n][k]
    const unsigned short* __restrict__ U2t,   // [256][256] bf16 [n][k]
    const float* __restrict__ b2,             // [256]
    int* flags,                               // [64], zeroed before launch
    float* __restrict__ out_last)             // [64][256] f32
{
    const int bid = blockIdx.x;
    const int tid = threadIdx.x;
    const int w   = tid >> 6;       // 0..7
    const int rw  = w & 3;          // role sub-wave
    const int L   = tid & 63;
    const int col = tid & 255;      // 0..255 in both halves
    const int q   = L >> 4;
    const int ml  = L & 15;

    __shared__ unsigned short hsh[2][256];

    if (bid < 64) {
        // ================= producer =================
        const int b = bid;
        int* flagp = flags + b;

        // waves 0-3: U1 fragments; waves 4-7: W2 fragments (one set per wave!)
        bf16x8 Bf[4][8];
        const unsigned short* Bsrc = (w < 4) ? U1t : W2t;
#pragma unroll
        for (int i = 0; i < 4; ++i) {
            const unsigned short* up = Bsrc + (size_t)((rw * 4 + i) * 16 + ml) * 256 + q * 8;
#pragma unroll
            for (int kt = 0; kt < 8; ++kt)
                Bf[i][kt] = *(const bf16x8*)(up + kt * 32);
        }
        if (tid < 256) hsh[0][tid] = 0;

        const float* xb  = xw + (size_t)b * 512 * 256 + col;
        const float* xpf = xb + 4 * 256;
        float xq0 = 0.f, xq1 = 0.f, xq2 = 0.f, xq3 = 0.f;
        if (w < 4) { xq0 = xb[0]; xq1 = xb[256]; xq2 = xb[512]; xq3 = xb[768]; }
        const float b2c = (w >= 4) ? b2[col] : 0.f;
        float* pst = xw + ((size_t)b * 512 * 256 + col) - 256;   // row -1; bumped per tick
        __syncthreads();

#define PTICK(RP, XQ, PF, ST)                                                        \
    {                                                                                \
        if (w < 4) {                                                                 \
            bf16x8 af[8];                                                            \
            _Pragma("unroll")                                                        \
            for (int kt = 0; kt < 8; ++kt)                                           \
                af[kt] = *(const bf16x8*)&hsh[RP][kt * 32 + q * 8];                  \
            float xnew = 0.f;                                                        \
            if (PF) { xnew = *xpf; xpf += 256; }                                     \
            f32x4 accA[4] = {}, accB[4] = {};                                        \
            _Pragma("unroll")                                                        \
            for (int kt = 0; kt < 8; kt += 2) {                                      \
                _Pragma("unroll")                                                    \
                for (int i = 0; i < 4; ++i)                                          \
                    accA[i] = __builtin_amdgcn_mfma_f32_16x16x32_bf16(af[kt], Bf[i][kt], accA[i], 0, 0, 0);       \
                _Pragma("unroll")                                                    \
                for (int i = 0; i < 4; ++i)                                          \
                    accB[i] = __builtin_amdgcn_mfma_f32_16x16x32_bf16(af[kt + 1], Bf[i][kt + 1], accB[i], 0, 0, 0); \
            }                                                                        \
            float z  = selq(accA, q) + selq(accB, q) + XQ;                           \
            float e  = __expf(2.f * z);           /* tanh(z) = 1 - 2/(e^{2z}+1) */   \
            float hn = 1.f - 2.f * __builtin_amdgcn_rcpf(e + 1.f);                   \
            hsh[(RP) ^ 1][col] = f2bf(hn);                                           \
            XQ = xnew;                                                               \
        } else {                                                                     \
            if (ST) {                                                                \
                bf16x8 af[8];                                                        \
                _Pragma("unroll")                                                    \
                for (int kt = 0; kt < 8; ++kt)                                       \
                    af[kt] = *(const bf16x8*)&hsh[RP][kt * 32 + q * 8];              \
                f32x4 aWA[4] = {}, aWB[4] = {};                                      \
                _Pragma("unroll")                                                    \
                for (int kt = 0; kt < 8; kt += 2) {                                  \
                    _Pragma("unroll")                                                \
                    for (int i = 0; i < 4; ++i)                                      \
                        aWA[i] = __builtin_amdgcn_mfma_f32_16x16x32_bf16(af[kt], Bf[i][kt], aWA[i], 0, 0, 0);       \
                    _Pragma("unroll")                                                \
                    for (int i = 0; i < 4; ++i)                                      \
                        aWB[i] = __builtin_amdgcn_mfma_f32_16x16x32_bf16(af[kt + 1], Bf[i][kt + 1], aWB[i], 0, 0, 0); \
                }                                                                    \
                *pst = selq(aWA, q) + selq(aWB, q) + b2c;                            \
            }                                                                        \
            pst += 256;                                                              \
        }                                                                            \
        barrier_lds_only();                                                          \
    }

        // group 0 (ticks 0..7): tick 0 has no p[-1] store
        PTICK(0, xq0, 1, 0) PTICK(1, xq1, 1, 1) PTICK(0, xq2, 1, 1) PTICK(1, xq3, 1, 1)
        PTICK(0, xq0, 1, 1) PTICK(1, xq1, 1, 1) PTICK(0, xq2, 1, 1) PTICK(1, xq3, 1, 1)
        asm volatile("s_waitcnt vmcnt(0)" ::: "memory");
        __builtin_amdgcn_s_barrier();
        if (tid == 0)
            __hip_atomic_store(flagp, 7, __ATOMIC_RELEASE, __HIP_MEMORY_SCOPE_AGENT);

        for (int g = 1; g < 63; ++g) {         // ticks 8g..8g+7
            PTICK(0, xq0, 1, 1) PTICK(1, xq1, 1, 1) PTICK(0, xq2, 1, 1) PTICK(1, xq3, 1, 1)
            PTICK(0, xq0, 1, 1) PTICK(1, xq1, 1, 1) PTICK(0, xq2, 1, 1) PTICK(1, xq3, 1, 1)
            asm volatile("s_waitcnt vmcnt(0)" ::: "memory");
            __builtin_amdgcn_s_barrier();
            if (tid == 0)
                __hip_atomic_store(flagp, 8 * g + 7, __ATOMIC_RELEASE, __HIP_MEMORY_SCOPE_AGENT);
        }
        // final group: ticks 504..507 prefetch rows 508..511; 508..511 no prefetch
        PTICK(0, xq0, 1, 1) PTICK(1, xq1, 1, 1) PTICK(0, xq2, 1, 1) PTICK(1, xq3, 1, 1)
        PTICK(0, xq0, 0, 1) PTICK(1, xq1, 0, 1) PTICK(0, xq2, 0, 1) PTICK(1, xq3, 0, 1)
        // tail: p[511] from h1[511] (in hsh[0]); pst now points at row 511
        if (w >= 4) {
            bf16x8 af[8];
#pragma unroll
            for (int kt = 0; kt < 8; ++kt)
                af[kt] = *(const bf16x8*)&hsh[0][kt * 32 + q * 8];
            f32x4 aWA[4] = {}, aWB[4] = {};
#pragma unroll
            for (int kt = 0; kt < 8; kt += 2) {
#pragma unroll
                for (int i = 0; i < 4; ++i)
                    aWA[i] = __builtin_amdgcn_mfma_f32_16x16x32_bf16(af[kt], Bf[i][kt], aWA[i], 0, 0, 0);
#pragma unroll
                for (int i = 0; i < 4; ++i)
                    aWB[i] = __builtin_amdgcn_mfma_f32_16x16x32_bf16(af[kt + 1], Bf[i][kt + 1], aWB[i], 0, 0, 0);
            }
            *pst = selq(aWA, q) + selq(aWB, q) + b2c;
        }
        barrier_lds_only();
        asm volatile("s_waitcnt vmcnt(0)" ::: "memory");
        __builtin_amdgcn_s_barrier();
        if (tid == 0)
            __hip_atomic_store(flagp, 1024, __ATOMIC_RELEASE, __HIP_MEMORY_SCOPE_AGENT);
#undef PTICK

    } else {
        // ================= consumer =================
        const int b = bid - 64;
        int* flagp = flags + b;

        bf16x8 Bf[4][8];   // U2 fragments (waves 4-7 load too; harmless, unused)
#pragma unroll
        for (int i = 0; i < 4; ++i) {
            const unsigned short* up = U2t + (size_t)((rw * 4 + i) * 16 + ml) * 256 + q * 8;
#pragma unroll
            for (int kt = 0; kt < 8; ++kt)
                Bf[i][kt] = *(const bf16x8*)(up + kt * 32);
        }
        if (tid < 256) hsh[0][tid] = 0;
        const float* pbc = xw + (size_t)b * 512 * 256 + col;
        float lastv = 0.f;
        __syncthreads();

#define CTICK(RP, PV)                                                                \
    {                                                                                \
        if (w < 4) {                                                                 \
            bf16x8 af[8];                                                            \
            _Pragma("unroll")                                                        \
            for (int kt = 0; kt < 8; ++kt)                                           \
                af[kt] = *(const bf16x8*)&hsh[RP][kt * 32 + q * 8];                  \
            f32x4 accA[4] = {}, accB[4] = {};                                        \
            _Pragma("unroll")                                                        \
            for (int kt = 0; kt < 8; kt += 2) {                                      \
                _Pragma("unroll")                                                    \
                for (int i = 0; i < 4; ++i)                                          \
                    accA[i] = __builtin_amdgcn_mfma_f32_16x16x32_bf16(af[kt], Bf[i][kt], accA[i], 0, 0, 0);       \
                _Pragma("unroll")                                                    \
                for (int i = 0; i < 4; ++i)                                          \
                    accB[i] = __builtin_amdgcn_mfma_f32_16x16x32_bf16(af[kt + 1], Bf[i][kt + 1], accB[i], 0, 0, 0); \
            }                                                                        \
            float z  = selq(accA, q) + selq(accB, q) + (PV);                         \
            float e  = __expf(2.f * z);                                              \
            float hn = 1.f - 2.f * __builtin_amdgcn_rcpf(e + 1.f);                   \
            lastv = hn;                                                              \
            hsh[(RP) ^ 1][col] = f2bf(hn);                                           \
        }                                                                            \
        barrier_lds_only();                                                          \
    }

        for (int c = 0; c < 32; ++c) {
            const int t0 = c * 16;
            if (tid == 0) {
                int it = 0;   // bounded spin: failure => wrong answer, never a hang
                while (__hip_atomic_load(flagp, __ATOMIC_ACQUIRE, __HIP_MEMORY_SCOPE_AGENT) < t0 + 16) {
                    __builtin_amdgcn_s_sleep(2);
                    if (++it > (1 << 17)) break;
                }
            }
            __syncthreads();
            float pv[16];
            if (w < 4) {
#pragma unroll
                for (int j = 0; j < 16; ++j)
                    pv[j] = pbc[(size_t)(t0 + j) << 8];
            }
            CTICK(0, pv[0])  CTICK(1, pv[1])  CTICK(0, pv[2])  CTICK(1, pv[3])
            CTICK(0, pv[4])  CTICK(1, pv[5])  CTICK(0, pv[6])  CTICK(1, pv[7])
            CTICK(0, pv[8])  CTICK(1, pv[9])  CTICK(0, pv[10]) CTICK(1, pv[11])
            CTICK(0, pv[12]) CTICK(1, pv[13]) CTICK(0, pv[14]) CTICK(1, pv[15])
        }
#undef CTICK

        if (w < 4) out_last[b * 256 + col] = lastv;
    }
}

// ---------- head: softmax(h2 @ Wd + bd) ----------
__global__ void head_kernel(const float* __restrict__ h2, const float* __restrict__ Wd,
                            const float* __restrict__ bd, float* __restrict__ out)
{
    int tid = threadIdx.x;         // 128 threads: b = tid>>1, c = tid&1
    int b = tid >> 1, c = tid & 1;
    float s = bd[c];
    for (int jj = 0; jj < 256; ++jj) s = fmaf(h2[b * 256 + jj], Wd[jj * 2 + c], s);
    __shared__ float lg[128];
    lg[tid] = s;
    __syncthreads();
    float o0 = lg[b * 2 + 0], o1 = lg[b * 2 + 1];
    float m = fmaxf(o0, o1);
    float z = __expf(o0 - m) + __expf(o1 - m);
    out[tid] = __expf(s - m) * __builtin_amdgcn_rcpf(z);
}

// ---------- launch ----------
extern "C" void kernel_launch(void* const* d_in, const int* in_sizes, int n_in,
                              void* d_out, int out_size, void* d_ws, size_t ws_size,
                              hipStream_t stream) {
    const int*   tokens = (const int*)d_in[0];
    const float* emb    = (const float*)d_in[1];
    const float* W1     = (const float*)d_in[2];
    const float* U1     = (const float*)d_in[3];
    const float* b1     = (const float*)d_in[4];
    const float* W2     = (const float*)d_in[5];
    const float* U2     = (const float*)d_in[6];
    const float* b2     = (const float*)d_in[7];
    const float* Wd     = (const float*)d_in[8];
    const float* bd     = (const float*)d_in[9];
    float* out = (float*)d_out;

    char* ws = (char*)d_ws;
    float*          xw  = (float*)ws;                                  // 32 MB (xw1 -> p in place)
    char*           p   = ws + 33554432 + 16777216;                    // weights (unchanged offsets)
    unsigned short* W1t = (unsigned short*)p;            p += 512 * 256 * 2;
    unsigned short* W2t = (unsigned short*)p;            p += 256 * 256 * 2;
    unsigned short* U1t = (unsigned short*)p;            p += 256 * 256 * 2;
    unsigned short* U2t = (unsigned short*)p;            p += 256 * 256 * 2;
    float*          h2  = (float*)p;                     p += 64 * 256 * 4;
    int*            flags = (int*)p;                     // 64 ints

    const int M = 64 * 512;   // 32768

    // flags must be 0 before the pipeline kernel (graph-capture-safe async memset)
    hipMemsetAsync(flags, 0, 64 * sizeof(int), stream);

    // K0: weight/recurrence transposes to bf16 [N][K]
    transpose4<<<dim3(512, 4), 256, 0, stream>>>(W1, W2, U1, U2, W1t, W2t, U1t, U2t);

    // K1: xw1 = emb[tokens] @ W1 + b1   (gather fused)
    gemm_mfma<true><<<dim3(256 / 64, M / 64), 256, 0, stream>>>(
        emb, tokens, W1t, b1, xw, M, 256, 512);

    // K2: 2-stage pipeline: scan1(+W2 GEMV in spare waves) -> p in xw -> scan2 -> h2
    rnn_pipe<<<128, 512, 0, stream>>>(xw, U1t, W2t, U2t, b2, flags, h2);

    // K3: softmax(h2 @ Wd + bd)
    head_kernel<<<1, 128, 0, stream>>>(h2, Wd, bd, out);
}

// Round 7
// 547.440 us; speedup vs baseline: 1.7960x; 1.1339x over previous
//
#include <hip/hip_runtime.h>

// ---------- types ----------
typedef __attribute__((ext_vector_type(8))) short bf16x8;
typedef __attribute__((ext_vector_type(4))) float f32x4;

static __device__ __forceinline__ unsigned short f2bf(float x) {
    unsigned int u = __float_as_uint(x);
    u += 0x7fffu + ((u >> 16) & 1u);   // RTNE, finite inputs
    return (unsigned short)(u >> 16);
}

static __device__ __forceinline__ float selq(const f32x4* a, int q) {
    return (q == 0) ? a[0][0] : (q == 1) ? a[1][0] : (q == 2) ? a[2][0] : a[3][0];
}

// Workgroup barrier WITHOUT vmcnt drain: LDS ordering only.
static __device__ __forceinline__ void barrier_lds_only() {
    __asm__ volatile("s_waitcnt lgkmcnt(0)\n\ts_barrier" ::: "memory");
}

// ---------- K0: four fp32->bf16 transposes in one launch ----------
__global__ void transpose4(const float* __restrict__ s0, const float* __restrict__ s1,
                           const float* __restrict__ s2, const float* __restrict__ s3,
                           unsigned short* __restrict__ d0, unsigned short* __restrict__ d1,
                           unsigned short* __restrict__ d2, unsigned short* __restrict__ d3) {
    int which = blockIdx.y;
    const float* src = which == 0 ? s0 : which == 1 ? s1 : which == 2 ? s2 : s3;
    unsigned short* dst = which == 0 ? d0 : which == 1 ? d1 : which == 2 ? d2 : d3;
    int K = (which == 0) ? 512 : 256;
    int idx = blockIdx.x * 256 + threadIdx.x;
    if (idx >= K * 256) return;
    int k = idx >> 8;          // N = 256
    int n = idx & 255;
    dst[n * K + k] = f2bf(src[idx]);
}

// ---------- K1 GEMM: C[M,N] = A[M,K] @ Bt[N,K]^T + bias, bf16 MFMA ----------
// Software-pipelined: tile k+1's global loads (incl. the emb gather) issue right
// after the barrier, hiding HBM latency under the MFMAs of tile k.
template<bool GATHER>
__global__ __launch_bounds__(256, 4) void gemm_mfma(
    const void* __restrict__ Aptr, const int* __restrict__ tokens,
    const unsigned short* __restrict__ Bt, const float* __restrict__ bias,
    float* __restrict__ C, int M, int N, int K)
{
    const int bn0 = blockIdx.x * 64;
    const int m0  = blockIdx.y * 64;
    const int tid = threadIdx.x;

    __shared__ unsigned short As[64 * 40];
    __shared__ unsigned short Bs[64 * 40];
    __shared__ int tok[64];

    const int r  = tid >> 2;
    const int c0 = (tid & 3) * 8;
    const int w  = tid >> 6;
    const int L  = tid & 63;
    const int ml = L & 15;
    const int q  = L >> 4;
    const int kq = q * 8;

    if (GATHER) {
        if (tid < 64) tok[tid] = tokens[m0 + tid];
        __syncthreads();
    }

    const float* af32 = nullptr;
    const unsigned short* abf = nullptr;
    if (GATHER) af32 = (const float*)Aptr + (size_t)tok[r] * K + c0;   // tok read ONCE
    else        abf  = (const unsigned short*)Aptr + (size_t)(m0 + r) * K + c0;
    const unsigned short* bsrc = Bt + (size_t)(bn0 + r) * K + c0;

    // prefetch tile 0
    float4 f0, f1; uint4 ab, bb;
    if (GATHER) { f0 = *(const float4*)af32; f1 = *(const float4*)(af32 + 4); af32 += 32; }
    else        { ab = *(const uint4*)abf; abf += 32; }
    bb = *(const uint4*)bsrc; bsrc += 32;

    f32x4 acc[4] = {};

    for (int k0 = 0; k0 < K; k0 += 32) {
        unsigned short tmp[8];
        if (GATHER) {
            tmp[0]=f2bf(f0.x); tmp[1]=f2bf(f0.y); tmp[2]=f2bf(f0.z); tmp[3]=f2bf(f0.w);
            tmp[4]=f2bf(f1.x); tmp[5]=f2bf(f1.y); tmp[6]=f2bf(f1.z); tmp[7]=f2bf(f1.w);
        } else {
            *(uint4*)tmp = ab;
        }
        *(uint4*)&As[r * 40 + c0] = *(const uint4*)tmp;
        *(uint4*)&Bs[r * 40 + c0] = bb;
        __syncthreads();

        if (k0 + 32 < K) {   // prefetch next tile under this tile's MFMAs
            if (GATHER) { f0 = *(const float4*)af32; f1 = *(const float4*)(af32 + 4); af32 += 32; }
            else        { ab = *(const uint4*)abf; abf += 32; }
            bb = *(const uint4*)bsrc; bsrc += 32;
        }

        bf16x8 av = *(const bf16x8*)&As[(16 * w + ml) * 40 + kq];
#pragma unroll
        for (int ns = 0; ns < 4; ++ns) {
            bf16x8 bv = *(const bf16x8*)&Bs[(ns * 16 + ml) * 40 + kq];
            acc[ns] = __builtin_amdgcn_mfma_f32_16x16x32_bf16(av, bv, acc[ns], 0, 0, 0);
        }
        __syncthreads();
    }

#pragma unroll
    for (int ns = 0; ns < 4; ++ns) {
        int gn = bn0 + ns * 16 + ml;
        float bv = bias[gn];
#pragma unroll
        for (int rr = 0; rr < 4; ++rr) {
            int gm = m0 + 16 * w + q * 4 + rr;
            C[(size_t)gm * N + gn] = acc[ns][rr] + bv;
        }
    }
}

// ---------- K2: 2-stage cross-CU pipeline, ring-buffered chunked GEMV ----------
// 128 blocks x 512 threads (8 waves), all co-resident.
// Producer blocks 0..63 (batch b):
//   waves 0-3: layer-1 scan; h1[t] -> LDS ring slot t%32 (replaces the old double
//              buffer; scan reads slot (t-1)%32 with compile-time offsets).
//   waves 4-7: ONCE PER 16-TICK GROUP g (at tick j=0, g>=1): batched GEMV
//              p[rows 16(g-1)..16g-1] = h1_chunk @ W2 + b2 as a real 16x256x256
//              GEMM (A rows distinct per lane -> 16x less LDS traffic + MFMA than
//              r6's per-tick matvec). Reads the ring half the scan is NOT writing.
//              Drain vmcnt(0) at j=8; tid0 releases flag=16g at j=9 (post-barrier).
//   Stores go in place into consumed xw rows (scan prefetch is 20+ rows ahead).
// Consumer blocks 64..127 (batch b-64, same XCD): unchanged from r6 (passed):
//   waves 0-3 scan2, per-16-tick flag-gated pv loads; waves 4-7 barrier-idle.
// REGISTER RULE (r3/r4): one 128-reg fragment set per wave. All spins bounded.
__global__ __launch_bounds__(512) void rnn_pipe(
    float* xw,                                // [64][512][256] f32: xw1, rows become p
    const unsigned short* __restrict__ U1t,   // [256][256] bf16 [n][k]
    const unsigned short* __restrict__ W2t,   // [256][256] bf16 [n][k]
    const unsigned short* __restrict__ U2t,   // [256][256] bf16 [n][k]
    const float* __restrict__ b2,             // [256]
    int* flags,                               // [64], zeroed before launch
    float* __restrict__ out_last)             // [64][256] f32
{
    const int bid = blockIdx.x;
    const int tid = threadIdx.x;
    const int w   = tid >> 6;       // 0..7
    const int rw  = w & 3;          // role sub-wave
    const int L   = tid & 63;
    const int col = tid & 255;
    const int q   = L >> 4;
    const int ml  = L & 15;

    __shared__ unsigned short ring[32][256];   // 16 KB h1 ring (producer) / hsh (consumer)

    if (bid < 64) {
        // ================= producer =================
        const int b = bid;
        int* flagp = flags + b;

        bf16x8 Bf[4][8];   // waves 0-3: U1; waves 4-7: W2 (ONE set per wave)
        const unsigned short* Bsrc = (w < 4) ? U1t : W2t;
#pragma unroll
        for (int i = 0; i < 4; ++i) {
            const unsigned short* up = Bsrc + (size_t)((rw * 4 + i) * 16 + ml) * 256 + q * 8;
#pragma unroll
            for (int kt = 0; kt < 8; ++kt)
                Bf[i][kt] = *(const bf16x8*)(up + kt * 32);
        }
        if (tid < 256) ring[31][tid] = 0;      // h1[-1] = 0

        const float* xpf = xw + (size_t)b * 512 * 256 + col;
        float xq[4];
        float b2v[4];
        if (w < 4) {
            xq[0] = xpf[0]; xq[1] = xpf[256]; xq[2] = xpf[512]; xq[3] = xpf[768];
            xpf += 4 * 256;
        } else {
#pragma unroll
            for (int i = 0; i < 4; ++i) b2v[i] = b2[rw * 64 + i * 16 + ml];
        }
        float* pb = xw + (size_t)b * 512 * 256;
        __syncthreads();

        for (int g = 0; g < 32; ++g) {
            const int half = g & 1;
#pragma unroll
            for (int j = 0; j < 16; ++j) {
                if (w < 4) {
                    // -------- scan tick t = 16g + j --------
                    const int slot_r = (j == 0) ? ((half ^ 1) * 16 + 15) : (half * 16 + j - 1);
                    bf16x8 af[8];
#pragma unroll
                    for (int kt = 0; kt < 8; ++kt)
                        af[kt] = *(const bf16x8*)&ring[slot_r][kt * 32 + q * 8];
                    float xnew = *xpf; xpf += 256;   // unconditional: overreads <=16KB of
                                                     // never-consumed workspace at the end
                    f32x4 accA[4] = {}, accB[4] = {};
#pragma unroll
                    for (int kt = 0; kt < 8; kt += 2) {
#pragma unroll
                        for (int i = 0; i < 4; ++i)
                            accA[i] = __builtin_amdgcn_mfma_f32_16x16x32_bf16(af[kt], Bf[i][kt], accA[i], 0, 0, 0);
#pragma unroll
                        for (int i = 0; i < 4; ++i)
                            accB[i] = __builtin_amdgcn_mfma_f32_16x16x32_bf16(af[kt + 1], Bf[i][kt + 1], accB[i], 0, 0, 0);
                    }
                    float z  = selq(accA, q) + selq(accB, q) + xq[j & 3];
                    float e  = __expf(2.f * z);       /* tanh(z) = 1 - 2/(e^{2z}+1) */
                    float hn = 1.f - 2.f * __builtin_amdgcn_rcpf(e + 1.f);
                    ring[half * 16 + j][col] = f2bf(hn);
                    xq[j & 3] = xnew;
                } else {
                    if (j == 0 && g > 0) {
                        // -------- chunked GEMV: rows 16(g-1)..16g-1 --------
                        const int half2 = half ^ 1;
                        const int t0 = (g - 1) * 16;
                        bf16x8 af[8];
#pragma unroll
                        for (int kt = 0; kt < 8; ++kt)
                            af[kt] = *(const bf16x8*)&ring[half2 * 16 + ml][kt * 32 + q * 8];
                        f32x4 acc[4] = {};
#pragma unroll
                        for (int kt = 0; kt < 8; ++kt)
#pragma unroll
                            for (int i = 0; i < 4; ++i)
                                acc[i] = __builtin_amdgcn_mfma_f32_16x16x32_bf16(af[kt], Bf[i][kt], acc[i], 0, 0, 0);
                        // C map (K1-verified): row = q*4+rr, col = rw*64+i*16+ml
                        float* ps = pb + (size_t)t0 * 256 + q * 1024 + rw * 64 + ml;
#pragma unroll
                        for (int i = 0; i < 4; ++i)
#pragma unroll
                            for (int rr = 0; rr < 4; ++rr)
                                ps[rr * 256 + i * 16] = acc[i][rr] + b2v[i];
                    }
                    if (j == 8 && g > 0)
                        asm volatile("s_waitcnt vmcnt(0)" ::: "memory");
                }
                if (j == 9 && g > 0 && tid == 0)
                    __hip_atomic_store(flagp, 16 * g, __ATOMIC_RELEASE, __HIP_MEMORY_SCOPE_AGENT);
                barrier_lds_only();
            }
        }
        // tail: chunk 31 (rows 496..511, ring slots 16..31)
        if (w >= 4) {
            bf16x8 af[8];
#pragma unroll
            for (int kt = 0; kt < 8; ++kt)
                af[kt] = *(const bf16x8*)&ring[16 + ml][kt * 32 + q * 8];
            f32x4 acc[4] = {};
#pragma unroll
            for (int kt = 0; kt < 8; ++kt)
#pragma unroll
                for (int i = 0; i < 4; ++i)
                    acc[i] = __builtin_amdgcn_mfma_f32_16x16x32_bf16(af[kt], Bf[i][kt], acc[i], 0, 0, 0);
            float* ps = pb + (size_t)496 * 256 + q * 1024 + rw * 64 + ml;
#pragma unroll
            for (int i = 0; i < 4; ++i)
#pragma unroll
                for (int rr = 0; rr < 4; ++rr)
                    ps[rr * 256 + i * 16] = acc[i][rr] + b2v[i];
            asm volatile("s_waitcnt vmcnt(0)" ::: "memory");
        }
        __builtin_amdgcn_s_barrier();
        if (tid == 0)
            __hip_atomic_store(flagp, 512, __ATOMIC_RELEASE, __HIP_MEMORY_SCOPE_AGENT);

    } else {
        // ================= consumer (unchanged from r6, passed) =================
        const int b = bid - 64;
        int* flagp = flags + b;
        unsigned short (*hsh)[256] = ring;

        bf16x8 Bf[4][8];   // U2 fragments
#pragma unroll
        for (int i = 0; i < 4; ++i) {
            const unsigned short* up = U2t + (size_t)((rw * 4 + i) * 16 + ml) * 256 + q * 8;
#pragma unroll
            for (int kt = 0; kt < 8; ++kt)
                Bf[i][kt] = *(const bf16x8*)(up + kt * 32);
        }
        if (tid < 256) hsh[0][tid] = 0;
        const float* pbc = xw + (size_t)b * 512 * 256 + col;
        float lastv = 0.f;
        __syncthreads();

#define CTICK(RP, PV)                                                                \
    {                                                                                \
        if (w < 4) {                                                                 \
            bf16x8 af[8];                                                            \
            _Pragma("unroll")                                                        \
            for (int kt = 0; kt < 8; ++kt)                                           \
                af[kt] = *(const bf16x8*)&hsh[RP][kt * 32 + q * 8];                  \
            f32x4 accA[4] = {}, accB[4] = {};                                        \
            _Pragma("unroll")                                                        \
            for (int kt = 0; kt < 8; kt += 2) {                                      \
                _Pragma("unroll")                                                    \
                for (int i = 0; i < 4; ++i)                                          \
                    accA[i] = __builtin_amdgcn_mfma_f32_16x16x32_bf16(af[kt], Bf[i][kt], accA[i], 0, 0, 0);       \
                _Pragma("unroll")                                                    \
                for (int i = 0; i < 4; ++i)                                          \
                    accB[i] = __builtin_amdgcn_mfma_f32_16x16x32_bf16(af[kt + 1], Bf[i][kt + 1], accB[i], 0, 0, 0); \
            }                                                                        \
            float z  = selq(accA, q) + selq(accB, q) + (PV);                         \
            float e  = __expf(2.f * z);                                              \
            float hn = 1.f - 2.f * __builtin_amdgcn_rcpf(e + 1.f);                   \
            lastv = hn;                                                              \
            hsh[(RP) ^ 1][col] = f2bf(hn);                                           \
        }                                                                            \
        barrier_lds_only();                                                          \
    }

        for (int c = 0; c < 32; ++c) {
            const int t0 = c * 16;
            if (tid == 0) {
                int it = 0;   // bounded spin: failure => wrong answer, never a hang
                while (__hip_atomic_load(flagp, __ATOMIC_ACQUIRE, __HIP_MEMORY_SCOPE_AGENT) < t0 + 16) {
                    __builtin_amdgcn_s_sleep(2);
                    if (++it > (1 << 17)) break;
                }
            }
            __syncthreads();
            float pv[16];
            if (w < 4) {
#pragma unroll
                for (int j = 0; j < 16; ++j)
                    pv[j] = pbc[(size_t)(t0 + j) << 8];
            }
            CTICK(0, pv[0])  CTICK(1, pv[1])  CTICK(0, pv[2])  CTICK(1, pv[3])
            CTICK(0, pv[4])  CTICK(1, pv[5])  CTICK(0, pv[6])  CTICK(1, pv[7])
            CTICK(0, pv[8])  CTICK(1, pv[9])  CTICK(0, pv[10]) CTICK(1, pv[11])
            CTICK(0, pv[12]) CTICK(1, pv[13]) CTICK(0, pv[14]) CTICK(1, pv[15])
        }
#undef CTICK

        if (w < 4) out_last[b * 256 + col] = lastv;
    }
}

// ---------- head: softmax(h2 @ Wd + bd) ----------
__global__ void head_kernel(const float* __restrict__ h2, const float* __restrict__ Wd,
                            const float* __restrict__ bd, float* __restrict__ out)
{
    int tid = threadIdx.x;         // 128 threads: b = tid>>1, c = tid&1
    int b = tid >> 1, c = tid & 1;
    float s = bd[c];
    for (int jj = 0; jj < 256; ++jj) s = fmaf(h2[b * 256 + jj], Wd[jj * 2 + c], s);
    __shared__ float lg[128];
    lg[tid] = s;
    __syncthreads();
    float o0 = lg[b * 2 + 0], o1 = lg[b * 2 + 1];
    float m = fmaxf(o0, o1);
    float z = __expf(o0 - m) + __expf(o1 - m);
    out[tid] = __expf(s - m) * __builtin_amdgcn_rcpf(z);
}

// ---------- launch ----------
extern "C" void kernel_launch(void* const* d_in, const int* in_sizes, int n_in,
                              void* d_out, int out_size, void* d_ws, size_t ws_size,
                              hipStream_t stream) {
    const int*   tokens = (const int*)d_in[0];
    const float* emb    = (const float*)d_in[1];
    const float* W1     = (const float*)d_in[2];
    const float* U1     = (const float*)d_in[3];
    const float* b1     = (const float*)d_in[4];
    const float* W2     = (const float*)d_in[5];
    const float* U2     = (const float*)d_in[6];
    const float* b2     = (const float*)d_in[7];
    const float* Wd     = (const float*)d_in[8];
    const float* bd     = (const float*)d_in[9];
    float* out = (float*)d_out;

    char* ws = (char*)d_ws;
    float*          xw  = (float*)ws;                                  // 32 MB (xw1 -> p in place)
    char*           p   = ws + 33554432 + 16777216;                    // weights (unchanged offsets)
    unsigned short* W1t = (unsigned short*)p;            p += 512 * 256 * 2;
    unsigned short* W2t = (unsigned short*)p;            p += 256 * 256 * 2;
    unsigned short* U1t = (unsigned short*)p;            p += 256 * 256 * 2;
    unsigned short* U2t = (unsigned short*)p;            p += 256 * 256 * 2;
    float*          h2  = (float*)p;                     p += 64 * 256 * 4;
    int*            flags = (int*)p;                     // 64 ints

    const int M = 64 * 512;   // 32768

    // flags must be 0 before the pipeline kernel (graph-capture-safe async memset)
    hipMemsetAsync(flags, 0, 64 * sizeof(int), stream);

    // K0: weight/recurrence transposes to bf16 [N][K]
    transpose4<<<dim3(512, 4), 256, 0, stream>>>(W1, W2, U1, U2, W1t, W2t, U1t, U2t);

    // K1: xw1 = emb[tokens] @ W1 + b1   (gather fused, prefetch-pipelined)
    gemm_mfma<true><<<dim3(256 / 64, M / 64), 256, 0, stream>>>(
        emb, tokens, W1t, b1, xw, M, 256, 512);

    // K2: 2-stage pipeline: scan1(+chunked W2 GEMV) -> p in xw -> scan2 -> h2
    rnn_pipe<<<128, 512, 0, stream>>>(xw, U1t, W2t, U2t, b2, flags, h2);

    // K3: softmax(h2 @ Wd + bd)
    head_kernel<<<1, 128, 0, stream>>>(h2, Wd, bd, out);
}